// Round 1
// baseline (119.945 us; speedup 1.0000x reference)
//
#include <hip/hip_runtime.h>
#include <hip/hip_bf16.h>

// Problem constants (from reference)
#define N_NODES 4096
#define F_IN    128
#define UNITS   64
#define HEADS   4

// ---------------------------------------------------------------------------
// Kernel 1: x = inputs @ w  [N,64], e1 = x @ attn_w1 [N,4], e2 = x @ attn_w2,
//           plus per-block partial column sums of x.
// 256 blocks x 256 threads; each block handles 16 rows.
// w staged in NATURAL [k][u] layout: column reads are ds_read_b32 at
// bank = u mod 32 -> 2-way aliasing = free (vs 8-way conflict of the
// transposed pitch-132 b128 reads). Staging is a straight float4 copy.
// ---------------------------------------------------------------------------
__global__ __launch_bounds__(256) void k1(const float* __restrict__ inputs,
                                          const float* __restrict__ w,
                                          const float* __restrict__ aw1,
                                          const float* __restrict__ aw2,
                                          float* __restrict__ x,
                                          float* __restrict__ e1,
                                          float* __restrict__ e2,
                                          float* __restrict__ partial) {
    __shared__ float w_lds[F_IN * UNITS];       // 32 KB, natural [k][u]
    __shared__ float in_lds[16 * F_IN];         // 8 KB
    __shared__ float x_lds[16 * 65];            // padded stride 65
    __shared__ float aw_lds[2 * UNITS * HEADS]; // aw1 then aw2 (2 KB)

    const int t = threadIdx.x;
    const int b = blockIdx.x;
    const int row0 = b * 16;

    // stage w (coalesced float4 copy, no transpose)
    {
        const float4* src = (const float4*)w;
        float4* dst = (float4*)w_lds;
        for (int idx = t; idx < F_IN * UNITS / 4; idx += 256) dst[idx] = src[idx];
    }
    // stage 16 input rows (coalesced float4)
    {
        const float4* src = (const float4*)(inputs + (size_t)row0 * F_IN);
        float4* dst = (float4*)in_lds;
        for (int idx = t; idx < 16 * F_IN / 4; idx += 256) dst[idx] = src[idx];
    }
    // stage attention vectors
    if (t < UNITS * HEADS) {
        aw_lds[t] = aw1[t];
        aw_lds[UNITS * HEADS + t] = aw2[t];
    }
    __syncthreads();

    // thread u = t&63 handles column u for rows rg*4 .. rg*4+3
    const int u = t & 63;
    const int rg = t >> 6;
    float acc0 = 0.f, acc1 = 0.f, acc2 = 0.f, acc3 = 0.f;
    const float4* r0 = (const float4*)(in_lds + (rg * 4 + 0) * F_IN);
    const float4* r1 = (const float4*)(in_lds + (rg * 4 + 1) * F_IN);
    const float4* r2 = (const float4*)(in_lds + (rg * 4 + 2) * F_IN);
    const float4* r3 = (const float4*)(in_lds + (rg * 4 + 3) * F_IN);
#pragma unroll 8
    for (int c = 0; c < F_IN / 4; c++) {
        const int k4 = c * 4;
        const float w0 = w_lds[(k4 + 0) * UNITS + u];   // 2-way bank alias: free
        const float w1 = w_lds[(k4 + 1) * UNITS + u];
        const float w2 = w_lds[(k4 + 2) * UNITS + u];
        const float w3 = w_lds[(k4 + 3) * UNITS + u];
        float4 a;
        a = r0[c]; acc0 = fmaf(a.w, w3, fmaf(a.z, w2, fmaf(a.y, w1, fmaf(a.x, w0, acc0))));
        a = r1[c]; acc1 = fmaf(a.w, w3, fmaf(a.z, w2, fmaf(a.y, w1, fmaf(a.x, w0, acc1))));
        a = r2[c]; acc2 = fmaf(a.w, w3, fmaf(a.z, w2, fmaf(a.y, w1, fmaf(a.x, w0, acc2))));
        a = r3[c]; acc3 = fmaf(a.w, w3, fmaf(a.z, w2, fmaf(a.y, w1, fmaf(a.x, w0, acc3))));
    }
    x_lds[(rg * 4 + 0) * 65 + u] = acc0;
    x_lds[(rg * 4 + 1) * 65 + u] = acc1;
    x_lds[(rg * 4 + 2) * 65 + u] = acc2;
    x_lds[(rg * 4 + 3) * 65 + u] = acc3;
    x[(size_t)(row0 + rg * 4 + 0) * UNITS + u] = acc0;
    x[(size_t)(row0 + rg * 4 + 1) * UNITS + u] = acc1;
    x[(size_t)(row0 + rg * 4 + 2) * UNITS + u] = acc2;
    x[(size_t)(row0 + rg * 4 + 3) * UNITS + u] = acc3;
    __syncthreads();

    // e1/e2: 16 rows x 4 heads x 2 matrices = 128 tasks
    if (t < 128) {
        const int r = t >> 3;
        const int rem = t & 7;
        const int h = rem & 3;
        const bool first = rem < 4;
        const float* aw = aw_lds + (first ? 0 : UNITS * HEADS);
        float s = 0.f;
#pragma unroll 8
        for (int uu = 0; uu < UNITS; uu++)
            s += x_lds[r * 65 + uu] * aw[uu * HEADS + h];
        (first ? e1 : e2)[(size_t)(row0 + r) * HEADS + h] = s;
    }

    // partial column sums of x over this block's 16 rows
    if (t < 64) {
        float s = 0.f;
#pragma unroll
        for (int r = 0; r < 16; r++) s += x_lds[r * 65 + t];
        partial[b * 64 + t] = s;
    }
}

// ---------------------------------------------------------------------------
// Kernel 1b: S[u] = sum over 256 block-partials (256 threads, 4-way split)
// ---------------------------------------------------------------------------
__global__ __launch_bounds__(256) void k1b(const float* __restrict__ partial,
                                           float* __restrict__ S) {
    __shared__ float red[4][64];
    const int u = threadIdx.x & 63;
    const int q = threadIdx.x >> 6;
    float s = 0.f;
#pragma unroll 8
    for (int b = q; b < 256; b += 4) s += partial[b * 64 + u];
    red[q][u] = s;
    __syncthreads();
    if (threadIdx.x < 64) S[u] = red[0][u] + red[1][u] + red[2][u] + red[3][u];
}

// ---------------------------------------------------------------------------
// Kernel 2: per row i.
//   - ballot-based neighbor compaction (1 LDS atomic per WAVE, not per edge)
//   - wave w == head w; after one barrier the waves are fully independent:
//     no per-chunk stage-to-LDS, no per-chunk barriers.
//   - x rows (1 MB total -> L2-resident, L1-hot across the 4 waves) are read
//     directly from global, coalesced 256 B per neighbor row.
//   - per-wave weights shared via a tiny LDS pair array, read back with
//     broadcast ds_read_b64 (uniform address -> conflict-free).
// LDS: 8 KB nbr + 2 KB pairs -> ~10.3 KB -> 8 blocks/CU resident (vs 6),
// keeping the HBM-bound adj scan saturated while compute hides underneath.
// out[i, h*64+u] = relu((S[u]+acc)/(N+den)).
// ---------------------------------------------------------------------------
__global__ __launch_bounds__(256) void k2(const float* __restrict__ adj,
                                          const float* __restrict__ x,
                                          const float* __restrict__ e1,
                                          const float* __restrict__ e2,
                                          const float* __restrict__ S,
                                          float* __restrict__ out) {
    __shared__ unsigned short nbr[N_NODES];   // 8 KB — worst case all neighbors
    __shared__ float2 pairs[HEADS][64];       // 2 KB — per-wave {j, wgt}
    __shared__ int cnt;

    const int i = blockIdx.x;
    const int t = threadIdx.x;
    const int lane = t & 63;
    const int h = t >> 6;                     // wave id == head

    if (t == 0) cnt = 0;
    __syncthreads();

    // scan adjacency row: issue all 4 float4 loads up front (latency overlap)
    const float4* arow = (const float4*)(adj + (size_t)i * N_NODES);
    const float4 v0 = arow[t];
    const float4 v1 = arow[t + 256];
    const float4 v2 = arow[t + 512];
    const float4 v3 = arow[t + 768];

    // ballots are wave-uniform -> live in SGPR pairs
    const unsigned long long b0  = __ballot(v0.x != 0.f);
    const unsigned long long b1  = __ballot(v0.y != 0.f);
    const unsigned long long b2  = __ballot(v0.z != 0.f);
    const unsigned long long b3  = __ballot(v0.w != 0.f);
    const unsigned long long b4  = __ballot(v1.x != 0.f);
    const unsigned long long b5  = __ballot(v1.y != 0.f);
    const unsigned long long b6  = __ballot(v1.z != 0.f);
    const unsigned long long b7  = __ballot(v1.w != 0.f);
    const unsigned long long b8  = __ballot(v2.x != 0.f);
    const unsigned long long b9  = __ballot(v2.y != 0.f);
    const unsigned long long b10 = __ballot(v2.z != 0.f);
    const unsigned long long b11 = __ballot(v2.w != 0.f);
    const unsigned long long b12 = __ballot(v3.x != 0.f);
    const unsigned long long b13 = __ballot(v3.y != 0.f);
    const unsigned long long b14 = __ballot(v3.z != 0.f);
    const unsigned long long b15 = __ballot(v3.w != 0.f);

    const int tot = __popcll(b0) + __popcll(b1) + __popcll(b2) + __popcll(b3)
                  + __popcll(b4) + __popcll(b5) + __popcll(b6) + __popcll(b7)
                  + __popcll(b8) + __popcll(b9) + __popcll(b10) + __popcll(b11)
                  + __popcll(b12) + __popcll(b13) + __popcll(b14) + __popcll(b15);

    int wbase = 0;
    if (lane == 0) wbase = atomicAdd(&cnt, tot);   // ONE atomic per wave
    wbase = __shfl(wbase, 0);

    const unsigned long long lt = (1ull << lane) - 1ull;
    {
        int off = wbase;
        const int g0 = t * 4, g1 = (t + 256) * 4, g2 = (t + 512) * 4, g3 = (t + 768) * 4;
        if (v0.x != 0.f) nbr[off + __popcll(b0  & lt)] = (unsigned short)(g0 + 0); off += __popcll(b0);
        if (v0.y != 0.f) nbr[off + __popcll(b1  & lt)] = (unsigned short)(g0 + 1); off += __popcll(b1);
        if (v0.z != 0.f) nbr[off + __popcll(b2  & lt)] = (unsigned short)(g0 + 2); off += __popcll(b2);
        if (v0.w != 0.f) nbr[off + __popcll(b3  & lt)] = (unsigned short)(g0 + 3); off += __popcll(b3);
        if (v1.x != 0.f) nbr[off + __popcll(b4  & lt)] = (unsigned short)(g1 + 0); off += __popcll(b4);
        if (v1.y != 0.f) nbr[off + __popcll(b5  & lt)] = (unsigned short)(g1 + 1); off += __popcll(b5);
        if (v1.z != 0.f) nbr[off + __popcll(b6  & lt)] = (unsigned short)(g1 + 2); off += __popcll(b6);
        if (v1.w != 0.f) nbr[off + __popcll(b7  & lt)] = (unsigned short)(g1 + 3); off += __popcll(b7);
        if (v2.x != 0.f) nbr[off + __popcll(b8  & lt)] = (unsigned short)(g2 + 0); off += __popcll(b8);
        if (v2.y != 0.f) nbr[off + __popcll(b9  & lt)] = (unsigned short)(g2 + 1); off += __popcll(b9);
        if (v2.z != 0.f) nbr[off + __popcll(b10 & lt)] = (unsigned short)(g2 + 2); off += __popcll(b10);
        if (v2.w != 0.f) nbr[off + __popcll(b11 & lt)] = (unsigned short)(g2 + 3); off += __popcll(b11);
        if (v3.x != 0.f) nbr[off + __popcll(b12 & lt)] = (unsigned short)(g3 + 0); off += __popcll(b12);
        if (v3.y != 0.f) nbr[off + __popcll(b13 & lt)] = (unsigned short)(g3 + 1); off += __popcll(b13);
        if (v3.z != 0.f) nbr[off + __popcll(b14 & lt)] = (unsigned short)(g3 + 2); off += __popcll(b14);
        if (v3.w != 0.f) nbr[off + __popcll(b15 & lt)] = (unsigned short)(g3 + 3); off += __popcll(b15);
    }
    __syncthreads();     // LAST barrier — waves are independent from here on

    const int n = cnt;
    const float e1h = e1[(size_t)i * HEADS + h];   // wave-uniform -> s_load

    float acc = 0.f;       // sum_k wgt[k] * x[j_k][u]   (u = lane)
    float den_lane = 0.f;  // per-lane partial of sum_k wgt[k]

    for (int base = 0; base < n; base += 64) {
        const int m = min(n - base, 64);
        int j = 0;
        float wv = 0.f;
        if (lane < m) {
            j = nbr[base + lane];
            const float e2h = e2[(size_t)j * HEADS + h];
            wv = __expf(fmaxf(e1h + e2h, 0.f)) - 1.f;
            den_lane += wv;
        }
        // wave-local share (DS pipe is in-order per wave; no barrier needed —
        // only this wave reads pairs[h][*])
        pairs[h][lane] = make_float2(__int_as_float(j), wv);

#pragma unroll 4
        for (int k = 0; k < m; k++) {
            const float2 p = pairs[h][k];             // broadcast ds_read_b64
            const int jk = __float_as_int(p.x);
            acc = fmaf(p.y, x[(jk << 6) + lane], acc); // coalesced 256 B, L1/L2-hit
        }
    }

    // wave-wide sum of den
    float den = den_lane;
    den += __shfl_xor(den, 32);
    den += __shfl_xor(den, 16);
    den += __shfl_xor(den, 8);
    den += __shfl_xor(den, 4);
    den += __shfl_xor(den, 2);
    den += __shfl_xor(den, 1);

    const float numer = S[lane] + acc;
    const float denom = (float)N_NODES + den;
    out[(size_t)i * (HEADS * UNITS) + t] = fmaxf(numer / denom, 0.f);
}

// ---------------------------------------------------------------------------
extern "C" void kernel_launch(void* const* d_in, const int* in_sizes, int n_in,
                              void* d_out, int out_size, void* d_ws, size_t ws_size,
                              hipStream_t stream) {
    const float* inputs = (const float*)d_in[0];
    const float* adj    = (const float*)d_in[1];
    const float* w      = (const float*)d_in[2];
    const float* aw1    = (const float*)d_in[3];
    const float* aw2    = (const float*)d_in[4];
    float* out = (float*)d_out;

    // workspace layout (floats): x[262144] | e1[16384] | e2[16384] | partial[16384] | S[64]
    float* ws = (float*)d_ws;
    float* x       = ws;
    float* e1      = ws + 262144;
    float* e2      = ws + 262144 + 16384;
    float* partial = ws + 262144 + 2 * 16384;
    float* S       = ws + 262144 + 3 * 16384;

    k1<<<256, 256, 0, stream>>>(inputs, w, aw1, aw2, x, e1, e2, partial);
    k1b<<<1, 256, 0, stream>>>(partial, S);
    k2<<<N_NODES, 256, 0, stream>>>(adj, x, e1, e2, S, out);
}

// Round 2
// 118.636 us; speedup vs baseline: 1.0110x; 1.0110x over previous
//
#include <hip/hip_runtime.h>
#include <hip/hip_bf16.h>

// Problem constants (from reference)
#define N_NODES 4096
#define F_IN    128
#define UNITS   64
#define HEADS   4
#define K2_CHUNK 256   // neighbor chunk (typical n ~41, max ~75 -> single chunk)

// ---------------------------------------------------------------------------
// Kernel 1: x = inputs @ w  [N,64], e1 = x @ attn_w1 [N,4], e2 = x @ attn_w2,
//           plus per-block partial column sums of x.
// 512 blocks x 256 threads; each block handles 8 rows -> 2 blocks/CU
// (round-1 ran 1 block/CU = 1 wave/SIMD, zero latency hiding).
// w staged in NATURAL [k][u] layout: column reads are ds_read_b32 at
// bank = u mod 32 -> 2-way aliasing = free.
// ---------------------------------------------------------------------------
__global__ __launch_bounds__(256) void k1(const float* __restrict__ inputs,
                                          const float* __restrict__ w,
                                          const float* __restrict__ aw1,
                                          const float* __restrict__ aw2,
                                          float* __restrict__ x,
                                          float* __restrict__ e1,
                                          float* __restrict__ e2,
                                          float* __restrict__ partial) {
    __shared__ float w_lds[F_IN * UNITS];       // 32 KB, natural [k][u]
    __shared__ float in_lds[8 * F_IN];          // 4 KB
    __shared__ float x_lds[8 * 65];             // padded stride 65
    __shared__ float aw_lds[2 * UNITS * HEADS]; // aw1 then aw2 (2 KB)

    const int t = threadIdx.x;
    const int b = blockIdx.x;
    const int row0 = b * 8;

    // stage w (coalesced float4 copy, no transpose)
    {
        const float4* src = (const float4*)w;
        float4* dst = (float4*)w_lds;
        for (int idx = t; idx < F_IN * UNITS / 4; idx += 256) dst[idx] = src[idx];
    }
    // stage 8 input rows (coalesced float4: 256 float4s, one per thread)
    {
        const float4* src = (const float4*)(inputs + (size_t)row0 * F_IN);
        float4* dst = (float4*)in_lds;
        dst[t] = src[t];
    }
    // stage attention vectors
    if (t < UNITS * HEADS) {
        aw_lds[t] = aw1[t];
        aw_lds[UNITS * HEADS + t] = aw2[t];
    }
    __syncthreads();

    // thread u = t&63 handles column u for rows rg*2, rg*2+1
    const int u = t & 63;
    const int rg = t >> 6;
    float acc0 = 0.f, acc1 = 0.f;
    const float4* r0 = (const float4*)(in_lds + (rg * 2 + 0) * F_IN);
    const float4* r1 = (const float4*)(in_lds + (rg * 2 + 1) * F_IN);
#pragma unroll 8
    for (int c = 0; c < F_IN / 4; c++) {
        const int k4 = c * 4;
        const float w0 = w_lds[(k4 + 0) * UNITS + u];   // 2-way bank alias: free
        const float w1 = w_lds[(k4 + 1) * UNITS + u];
        const float w2 = w_lds[(k4 + 2) * UNITS + u];
        const float w3 = w_lds[(k4 + 3) * UNITS + u];
        float4 a;
        a = r0[c]; acc0 = fmaf(a.w, w3, fmaf(a.z, w2, fmaf(a.y, w1, fmaf(a.x, w0, acc0))));
        a = r1[c]; acc1 = fmaf(a.w, w3, fmaf(a.z, w2, fmaf(a.y, w1, fmaf(a.x, w0, acc1))));
    }
    x_lds[(rg * 2 + 0) * 65 + u] = acc0;
    x_lds[(rg * 2 + 1) * 65 + u] = acc1;
    x[(size_t)(row0 + rg * 2 + 0) * UNITS + u] = acc0;
    x[(size_t)(row0 + rg * 2 + 1) * UNITS + u] = acc1;
    __syncthreads();

    // e1/e2: 8 rows x 4 heads x 2 matrices = 64 tasks
    if (t < 64) {
        const int r = t >> 3;
        const int rem = t & 7;
        const int h = rem & 3;
        const bool first = rem < 4;
        const float* aw = aw_lds + (first ? 0 : UNITS * HEADS);
        float s = 0.f;
#pragma unroll 8
        for (int uu = 0; uu < UNITS; uu++)
            s += x_lds[r * 65 + uu] * aw[uu * HEADS + h];
        (first ? e1 : e2)[(size_t)(row0 + r) * HEADS + h] = s;
    }

    // partial column sums of x over this block's 8 rows
    if (t < 64) {
        float s = 0.f;
#pragma unroll
        for (int r = 0; r < 8; r++) s += x_lds[r * 65 + t];
        partial[b * 64 + t] = s;
    }
}

// ---------------------------------------------------------------------------
// Kernel 1b: S[u] = sum over 512 block-partials (256 threads, 4-way split)
// ---------------------------------------------------------------------------
__global__ __launch_bounds__(256) void k1b(const float* __restrict__ partial,
                                           float* __restrict__ S) {
    __shared__ float red[4][64];
    const int u = threadIdx.x & 63;
    const int q = threadIdx.x >> 6;
    float s = 0.f;
#pragma unroll 8
    for (int b = q; b < 512; b += 4) s += partial[b * 64 + u];
    red[q][u] = s;
    __syncthreads();
    if (threadIdx.x < 64) S[u] = red[0][u] + red[1][u] + red[2][u] + red[3][u];
}

// ---------------------------------------------------------------------------
// Kernel 2: per row i.
//   - ballot-based neighbor compaction (1 LDS atomic per WAVE)
//   - phase A: all 4 head-weights per neighbor computed ONCE (float4 -> LDS),
//     per-thread den partials accumulated here (out of the hot loop)
//   - phase B: the 4 waves split the NEIGHBOR LIST (k = wave, wave+4, ...),
//     not the heads. Each x row is loaded once per block (was 4x), each lane
//     carries 4 head-accumulators. Inner loop per neighbor:
//     1 broadcast ds_read_b128 + 1 uniform nbr read + 1 coalesced b32 + 4 FMA.
//   - final 4-way cross-wave LDS reduction recombines (4 KB).
// LDS ~16.3 KB -> 8 blocks/CU resident; adj scan stays HBM-saturated.
// out[i, h*64+u] = relu((S[u]+acc_h)/(N+den_h)).
// ---------------------------------------------------------------------------
__global__ __launch_bounds__(256) void k2(const float* __restrict__ adj,
                                          const float* __restrict__ x,
                                          const float* __restrict__ e1,
                                          const float* __restrict__ e2,
                                          const float* __restrict__ S,
                                          float* __restrict__ out) {
    __shared__ unsigned short nbr[N_NODES];   // 8 KB — worst case all neighbors
    __shared__ float4 wgt[K2_CHUNK];          // 4 KB — per-neighbor head weights
    __shared__ float red[4][HEADS * UNITS];   // 4 KB — per-wave partial sums
    __shared__ float4 denred[4];              // per-wave den partials
    __shared__ int cnt;

    const int i = blockIdx.x;
    const int t = threadIdx.x;
    const int lane = t & 63;
    const int wid = t >> 6;

    if (t == 0) cnt = 0;
    __syncthreads();

    // scan adjacency row: issue all 4 float4 loads up front (latency overlap)
    const float4* arow = (const float4*)(adj + (size_t)i * N_NODES);
    const float4 v0 = arow[t];
    const float4 v1 = arow[t + 256];
    const float4 v2 = arow[t + 512];
    const float4 v3 = arow[t + 768];

    // ballots are wave-uniform -> live in SGPR pairs
    const unsigned long long b0  = __ballot(v0.x != 0.f);
    const unsigned long long b1  = __ballot(v0.y != 0.f);
    const unsigned long long b2  = __ballot(v0.z != 0.f);
    const unsigned long long b3  = __ballot(v0.w != 0.f);
    const unsigned long long b4  = __ballot(v1.x != 0.f);
    const unsigned long long b5  = __ballot(v1.y != 0.f);
    const unsigned long long b6  = __ballot(v1.z != 0.f);
    const unsigned long long b7  = __ballot(v1.w != 0.f);
    const unsigned long long b8  = __ballot(v2.x != 0.f);
    const unsigned long long b9  = __ballot(v2.y != 0.f);
    const unsigned long long b10 = __ballot(v2.z != 0.f);
    const unsigned long long b11 = __ballot(v2.w != 0.f);
    const unsigned long long b12 = __ballot(v3.x != 0.f);
    const unsigned long long b13 = __ballot(v3.y != 0.f);
    const unsigned long long b14 = __ballot(v3.z != 0.f);
    const unsigned long long b15 = __ballot(v3.w != 0.f);

    const int tot = __popcll(b0) + __popcll(b1) + __popcll(b2) + __popcll(b3)
                  + __popcll(b4) + __popcll(b5) + __popcll(b6) + __popcll(b7)
                  + __popcll(b8) + __popcll(b9) + __popcll(b10) + __popcll(b11)
                  + __popcll(b12) + __popcll(b13) + __popcll(b14) + __popcll(b15);

    int wbase = 0;
    if (lane == 0) wbase = atomicAdd(&cnt, tot);   // ONE atomic per wave
    wbase = __shfl(wbase, 0);

    const unsigned long long lt = (1ull << lane) - 1ull;
    {
        int off = wbase;
        const int g0 = t * 4, g1 = (t + 256) * 4, g2 = (t + 512) * 4, g3 = (t + 768) * 4;
        if (v0.x != 0.f) nbr[off + __popcll(b0  & lt)] = (unsigned short)(g0 + 0); off += __popcll(b0);
        if (v0.y != 0.f) nbr[off + __popcll(b1  & lt)] = (unsigned short)(g0 + 1); off += __popcll(b1);
        if (v0.z != 0.f) nbr[off + __popcll(b2  & lt)] = (unsigned short)(g0 + 2); off += __popcll(b2);
        if (v0.w != 0.f) nbr[off + __popcll(b3  & lt)] = (unsigned short)(g0 + 3); off += __popcll(b3);
        if (v1.x != 0.f) nbr[off + __popcll(b4  & lt)] = (unsigned short)(g1 + 0); off += __popcll(b4);
        if (v1.y != 0.f) nbr[off + __popcll(b5  & lt)] = (unsigned short)(g1 + 1); off += __popcll(b5);
        if (v1.z != 0.f) nbr[off + __popcll(b6  & lt)] = (unsigned short)(g1 + 2); off += __popcll(b6);
        if (v1.w != 0.f) nbr[off + __popcll(b7  & lt)] = (unsigned short)(g1 + 3); off += __popcll(b7);
        if (v2.x != 0.f) nbr[off + __popcll(b8  & lt)] = (unsigned short)(g2 + 0); off += __popcll(b8);
        if (v2.y != 0.f) nbr[off + __popcll(b9  & lt)] = (unsigned short)(g2 + 1); off += __popcll(b9);
        if (v2.z != 0.f) nbr[off + __popcll(b10 & lt)] = (unsigned short)(g2 + 2); off += __popcll(b10);
        if (v2.w != 0.f) nbr[off + __popcll(b11 & lt)] = (unsigned short)(g2 + 3); off += __popcll(b11);
        if (v3.x != 0.f) nbr[off + __popcll(b12 & lt)] = (unsigned short)(g3 + 0); off += __popcll(b12);
        if (v3.y != 0.f) nbr[off + __popcll(b13 & lt)] = (unsigned short)(g3 + 1); off += __popcll(b13);
        if (v3.z != 0.f) nbr[off + __popcll(b14 & lt)] = (unsigned short)(g3 + 2); off += __popcll(b14);
        if (v3.w != 0.f) nbr[off + __popcll(b15 & lt)] = (unsigned short)(g3 + 3); off += __popcll(b15);
    }
    __syncthreads();

    const int n = cnt;
    const float4 e1v = *(const float4*)(e1 + (size_t)i * HEADS);

    float a0 = 0.f, a1 = 0.f, a2 = 0.f, a3 = 0.f;   // per-head accumulators
    float4 dpart = make_float4(0.f, 0.f, 0.f, 0.f); // per-thread den partials

    for (int base = 0; base < n; base += K2_CHUNK) {
        const int m = min(n - base, K2_CHUNK);

        // phase A: weights for this chunk, one thread per neighbor
        for (int k = t; k < m; k += 256) {
            const int j = nbr[base + k];
            const float4 e2v = *(const float4*)(e2 + (size_t)j * HEADS);
            float4 wv;
            wv.x = __expf(fmaxf(e1v.x + e2v.x, 0.f)) - 1.f;
            wv.y = __expf(fmaxf(e1v.y + e2v.y, 0.f)) - 1.f;
            wv.z = __expf(fmaxf(e1v.z + e2v.z, 0.f)) - 1.f;
            wv.w = __expf(fmaxf(e1v.w + e2v.w, 0.f)) - 1.f;
            wgt[k] = wv;
            dpart.x += wv.x; dpart.y += wv.y; dpart.z += wv.z; dpart.w += wv.w;
        }
        __syncthreads();

        // phase B: waves split the neighbor list; x row loaded once per block
#pragma unroll 4
        for (int k = wid; k < m; k += 4) {
            const float4 p = wgt[k];                    // broadcast ds_read_b128
            const int j = nbr[base + k];                // uniform LDS read
            const float xv = x[(j << 6) + lane];        // coalesced 256 B, L1/L2-hit
            a0 = fmaf(p.x, xv, a0);
            a1 = fmaf(p.y, xv, a1);
            a2 = fmaf(p.z, xv, a2);
            a3 = fmaf(p.w, xv, a3);
        }
        __syncthreads();   // protect wgt before next chunk overwrites
    }

    // wave-reduce den partials (once, outside the hot loop)
    dpart.x += __shfl_xor(dpart.x, 32); dpart.y += __shfl_xor(dpart.y, 32);
    dpart.z += __shfl_xor(dpart.z, 32); dpart.w += __shfl_xor(dpart.w, 32);
    dpart.x += __shfl_xor(dpart.x, 16); dpart.y += __shfl_xor(dpart.y, 16);
    dpart.z += __shfl_xor(dpart.z, 16); dpart.w += __shfl_xor(dpart.w, 16);
    dpart.x += __shfl_xor(dpart.x, 8);  dpart.y += __shfl_xor(dpart.y, 8);
    dpart.z += __shfl_xor(dpart.z, 8);  dpart.w += __shfl_xor(dpart.w, 8);
    dpart.x += __shfl_xor(dpart.x, 4);  dpart.y += __shfl_xor(dpart.y, 4);
    dpart.z += __shfl_xor(dpart.z, 4);  dpart.w += __shfl_xor(dpart.w, 4);
    dpart.x += __shfl_xor(dpart.x, 2);  dpart.y += __shfl_xor(dpart.y, 2);
    dpart.z += __shfl_xor(dpart.z, 2);  dpart.w += __shfl_xor(dpart.w, 2);
    dpart.x += __shfl_xor(dpart.x, 1);  dpart.y += __shfl_xor(dpart.y, 1);
    dpart.z += __shfl_xor(dpart.z, 1);  dpart.w += __shfl_xor(dpart.w, 1);

    // per-wave partials -> LDS
    red[wid][0 * 64 + lane] = a0;
    red[wid][1 * 64 + lane] = a1;
    red[wid][2 * 64 + lane] = a2;
    red[wid][3 * 64 + lane] = a3;
    if (lane == 0) denred[wid] = dpart;
    __syncthreads();

    // thread t = (h, u): recombine 4 wave-partials
    const int h = wid;         // output head = wave id
    const int u = lane;
    const float accsum = red[0][h * 64 + u] + red[1][h * 64 + u]
                       + red[2][h * 64 + u] + red[3][h * 64 + u];
    const float* d0 = (const float*)&denred[0];
    const float* d1 = (const float*)&denred[1];
    const float* d2 = (const float*)&denred[2];
    const float* d3 = (const float*)&denred[3];
    const float den = d0[h] + d1[h] + d2[h] + d3[h];

    const float numer = S[u] + accsum;
    const float denom = (float)N_NODES + den;
    out[(size_t)i * (HEADS * UNITS) + t] = fmaxf(numer / denom, 0.f);
}

// ---------------------------------------------------------------------------
extern "C" void kernel_launch(void* const* d_in, const int* in_sizes, int n_in,
                              void* d_out, int out_size, void* d_ws, size_t ws_size,
                              hipStream_t stream) {
    const float* inputs = (const float*)d_in[0];
    const float* adj    = (const float*)d_in[1];
    const float* w      = (const float*)d_in[2];
    const float* aw1    = (const float*)d_in[3];
    const float* aw2    = (const float*)d_in[4];
    float* out = (float*)d_out;

    // workspace layout (floats): x[262144] | e1[16384] | e2[16384] | partial[32768] | S[64]
    float* ws = (float*)d_ws;
    float* x       = ws;
    float* e1      = ws + 262144;
    float* e2      = ws + 262144 + 16384;
    float* partial = ws + 262144 + 2 * 16384;
    float* S       = ws + 262144 + 2 * 16384 + 32768;

    k1<<<512, 256, 0, stream>>>(inputs, w, aw1, aw2, x, e1, e2, partial);
    k1b<<<1, 256, 0, stream>>>(partial, S);
    k2<<<N_NODES, 256, 0, stream>>>(adj, x, e1, e2, S, out);
}